// Round 3
// baseline (2921.508 us; speedup 1.0000x reference)
//
#include <hip/hip_runtime.h>

#define TPB   256
#define SHIFT 13
#define BINW  (1 << SHIFT)       // 8192 nodes per bin (32 KB LDS dense array)
#define MAXB  64                 // max bins per direction (N <= 512K)
#define SEGS  16                 // segments per bin in accumulate phase
#define CH    4096               // edges per partition chunk (= TPB * 16)

// ---- ws byte layout (fast path) ----
// [0, 2KB)        meta (uint): cnt[2][64] @0, base[2][64] @128, cur[2][64] @256
// [1MB, 24MB)     partials: float[wi][BINW], wi = (d*nb+bin)*SEGS+seg
// [24MB, 32MB)    norms: float norm0[N], norm1[N]
// [32MB, 32MB+16E) pairs: uint2 pairs0[E], pairs1[E]
#define OFF_PART  (1ull << 20)
#define OFF_NORM  (24ull << 20)
#define OFF_PAIRS (32ull << 20)

// ============================ fast path ============================

__global__ void ewn_meta_zero(unsigned* __restrict__ meta) {
    int i = blockIdx.x * blockDim.x + threadIdx.x;
    if (i < 512) meta[i] = 0u;
}

__global__ void ewn_count_kernel(const int* __restrict__ src,
                                 const int* __restrict__ dst,
                                 unsigned* __restrict__ meta, int E) {
    __shared__ unsigned h[4][2][MAXB];
    const int wv = threadIdx.x >> 6;
    for (int i = threadIdx.x; i < 4 * 2 * MAXB; i += blockDim.x)
        ((unsigned*)h)[i] = 0u;
    __syncthreads();
    long long gid = blockIdx.x * (long long)blockDim.x + threadIdx.x;
    long long stride = (long long)gridDim.x * blockDim.x;
    long long n4 = E >> 2;
    for (long long i = gid; i < n4; i += stride) {
        int4 s4 = ((const int4*)src)[i];
        int4 d4 = ((const int4*)dst)[i];
        atomicAdd(&h[wv][0][s4.x >> SHIFT], 1u);
        atomicAdd(&h[wv][0][s4.y >> SHIFT], 1u);
        atomicAdd(&h[wv][0][s4.z >> SHIFT], 1u);
        atomicAdd(&h[wv][0][s4.w >> SHIFT], 1u);
        atomicAdd(&h[wv][1][d4.x >> SHIFT], 1u);
        atomicAdd(&h[wv][1][d4.y >> SHIFT], 1u);
        atomicAdd(&h[wv][1][d4.z >> SHIFT], 1u);
        atomicAdd(&h[wv][1][d4.w >> SHIFT], 1u);
    }
    if (gid == 0) {
        for (long long j = n4 << 2; j < E; ++j) {
            atomicAdd(&h[wv][0][src[j] >> SHIFT], 1u);
            atomicAdd(&h[wv][1][dst[j] >> SHIFT], 1u);
        }
    }
    __syncthreads();
    for (int i = threadIdx.x; i < 2 * MAXB; i += blockDim.x) {
        int d = i >> 6, b = i & 63;
        unsigned tot = h[0][d][b] + h[1][d][b] + h[2][d][b] + h[3][d][b];
        if (tot) atomicAdd(&meta[d * MAXB + b], tot);
    }
}

__global__ void ewn_scan_kernel(unsigned* __restrict__ meta, const int* __restrict__ pN) {
    int nb = (*pN + BINW - 1) >> SHIFT;
    if (threadIdx.x < 2) {
        int d = threadIdx.x;
        unsigned run = 0;
        for (int b = 0; b < nb; ++b) {
            unsigned c = meta[d * MAXB + b];
            meta[128 + d * MAXB + b] = run;   // base
            meta[256 + d * MAXB + b] = run;   // cursor
            run += c;
        }
    }
}

__global__ void ewn_partition_kernel(const float* __restrict__ w,
                                     const int* __restrict__ src,
                                     const int* __restrict__ dst,
                                     unsigned* __restrict__ meta,
                                     uint2* __restrict__ pairs, int E) {
    __shared__ unsigned s_cnt[4][MAXB];
    __shared__ unsigned s_base[MAXB];
    const int tid = threadIdx.x, wv = tid >> 6;
    const int nchunks = (E + CH - 1) / CH;
    for (int c = blockIdx.x; c < nchunks; c += gridDim.x) {
        long long e0 = (long long)c * CH + (long long)tid * 16;
        float wr[16];
        int nd0[16], nd1[16];
        for (int j = 0; j < 4; ++j) {
            long long b = e0 + j * 4;
            if (b + 3 < E) {
                float4 w4 = *(const float4*)(w + b);
                int4 s4 = *(const int4*)(src + b);
                int4 d4 = *(const int4*)(dst + b);
                wr[j*4+0]=w4.x; wr[j*4+1]=w4.y; wr[j*4+2]=w4.z; wr[j*4+3]=w4.w;
                nd0[j*4+0]=s4.x; nd0[j*4+1]=s4.y; nd0[j*4+2]=s4.z; nd0[j*4+3]=s4.w;
                nd1[j*4+0]=d4.x; nd1[j*4+1]=d4.y; nd1[j*4+2]=d4.z; nd1[j*4+3]=d4.w;
            } else {
                for (int q = 0; q < 4; ++q) {
                    long long e = b + q;
                    if (e < E) { wr[j*4+q]=w[e]; nd0[j*4+q]=src[e]; nd1[j*4+q]=dst[e]; }
                    else       { nd0[j*4+q] = -1; nd1[j*4+q] = -1; }
                }
            }
        }
        for (int d = 0; d < 2; ++d) {
            for (int i = tid; i < 4 * MAXB; i += blockDim.x) ((unsigned*)s_cnt)[i] = 0u;
            __syncthreads();
            for (int k = 0; k < 16; ++k) {
                int n = d ? nd1[k] : nd0[k];
                if (n >= 0) atomicAdd(&s_cnt[wv][n >> SHIFT], 1u);
            }
            __syncthreads();
            if (tid < MAXB) {
                unsigned tot = s_cnt[0][tid] + s_cnt[1][tid] + s_cnt[2][tid] + s_cnt[3][tid];
                unsigned base = 0;
                if (tot) base = atomicAdd(&meta[256 + d * MAXB + tid], tot);
                s_base[tid] = base;
            }
            __syncthreads();
            uint2* pd = pairs + (long long)d * E;
            for (int k = 0; k < 16; ++k) {
                int n = d ? nd1[k] : nd0[k];
                if (n >= 0) {
                    unsigned slot = atomicAdd(&s_base[n >> SHIFT], 1u);
                    float wk = wr[k];
                    pd[slot] = make_uint2((unsigned)n, __float_as_uint(wk));
                }
            }
            __syncthreads();
        }
    }
}

__global__ void ewn_accum_kernel(const uint2* __restrict__ pairs,
                                 const unsigned* __restrict__ meta,
                                 float* __restrict__ part,
                                 const int* __restrict__ pN, int E) {
    __shared__ float acc[BINW];
    const int N = *pN;
    const int nb = (N + BINW - 1) >> SHIFT;
    const int items = nb * 2 * SEGS;
    for (int wi = blockIdx.x; wi < items; wi += gridDim.x) {
        int d = wi / (nb * SEGS);
        int rem = wi - d * nb * SEGS;
        int bin = rem / SEGS, seg = rem - bin * SEGS;
        unsigned base = meta[128 + d * MAXB + bin];
        unsigned len  = meta[d * MAXB + bin];
        unsigned s0 = base + (unsigned)(((unsigned long long)len * (unsigned)seg) / SEGS);
        unsigned s1 = base + (unsigned)(((unsigned long long)len * (unsigned)(seg + 1)) / SEGS);
        for (int i = threadIdx.x; i < BINW; i += blockDim.x) acc[i] = 0.0f;
        __syncthreads();
        const uint2* pd = pairs + (long long)d * E;
        const int lo = bin << SHIFT;
        for (unsigned i = s0 + threadIdx.x; i < s1; i += blockDim.x) {
            uint2 p = pd[i];
            atomicAdd(&acc[p.x - (unsigned)lo], __uint_as_float(p.y));
        }
        __syncthreads();
        float* dp = part + (long long)wi * BINW;
        for (int i = threadIdx.x; i < BINW; i += blockDim.x) dp[i] = acc[i];
        __syncthreads();
    }
}

__global__ void ewn_reduce_kernel(const float* __restrict__ part,
                                  float* __restrict__ norm,
                                  const int* __restrict__ pN) {
    const int N = *pN;
    const int nb = (N + BINW - 1) >> SHIFT;
    long long n2 = 2ll * N;
    for (long long i = blockIdx.x * (long long)blockDim.x + threadIdx.x; i < n2;
         i += (long long)gridDim.x * blockDim.x) {
        int d = (i >= N) ? 1 : 0;
        int n = (int)(i - (long long)d * N);
        int bin = n >> SHIFT, off = n & (BINW - 1);
        const float* p = part + ((long long)(d * nb + bin) * SEGS) * BINW + off;
        float s = 0.0f;
        for (int g = 0; g < SEGS; ++g) s += p[(long long)g * BINW];
        norm[i] = 1.0f / sqrtf(s);   // precise rsqrt (threshold 2e-4)
    }
}

__global__ void ewn_gather_kernel(const float* __restrict__ w,
                                  const int* __restrict__ src,
                                  const int* __restrict__ dst,
                                  const float* __restrict__ norm,
                                  const int* __restrict__ pN,
                                  float* __restrict__ out, int E) {
    const int N = *pN;
    const float* n0 = norm;
    const float* n1 = norm + N;
    int i = blockIdx.x * blockDim.x + threadIdx.x;
    long long i4 = (long long)i * 4;
    if (i4 + 3 < E) {
        float4 wv = *(const float4*)(w + i4);
        int4 sv = *(const int4*)(src + i4);
        int4 dv = *(const int4*)(dst + i4);
        float4 ov;
        ov.x = n0[sv.x] * n1[dv.x] * wv.x;
        ov.y = n0[sv.y] * n1[dv.y] * wv.y;
        ov.z = n0[sv.z] * n1[dv.z] * wv.z;
        ov.w = n0[sv.w] * n1[dv.w] * wv.w;
        *(float4*)(out + i4) = ov;
    } else if (i4 < E) {
        for (long long j = i4; j < E; ++j)
            out[j] = n0[src[j]] * n1[dst[j]] * w[j];
    }
}

// ============================ fallback path (proven, atomic) ============================

__global__ void ewn_fb_zero(float* __restrict__ deg, const int* __restrict__ pN) {
    int n2 = 2 * (*pN);
    for (int i = blockIdx.x * blockDim.x + threadIdx.x; i < n2; i += gridDim.x * blockDim.x)
        deg[i] = 0.0f;
}

__global__ void ewn_fb_scatter(const float* __restrict__ w, const int* __restrict__ src,
                               const int* __restrict__ dst, float* __restrict__ deg,
                               const int* __restrict__ pN, int E) {
    const int N = *pN;
    float* dout = deg;
    float* din = deg + N;
    int i = blockIdx.x * blockDim.x + threadIdx.x;
    long long i4 = (long long)i * 4;
    if (i4 + 3 < E) {
        float4 wv = *(const float4*)(w + i4);
        int4 sv = *(const int4*)(src + i4);
        int4 dv = *(const int4*)(dst + i4);
        atomicAdd(&dout[sv.x], wv.x); atomicAdd(&dout[sv.y], wv.y);
        atomicAdd(&dout[sv.z], wv.z); atomicAdd(&dout[sv.w], wv.w);
        atomicAdd(&din[dv.x], wv.x);  atomicAdd(&din[dv.y], wv.y);
        atomicAdd(&din[dv.z], wv.z);  atomicAdd(&din[dv.w], wv.w);
    } else if (i4 < E) {
        for (long long j = i4; j < E; ++j) {
            float wj = w[j];
            atomicAdd(&dout[src[j]], wj);
            atomicAdd(&din[dst[j]], wj);
        }
    }
}

__global__ void ewn_fb_norm(float* __restrict__ deg, const int* __restrict__ pN) {
    int n2 = 2 * (*pN);
    for (int i = blockIdx.x * blockDim.x + threadIdx.x; i < n2; i += gridDim.x * blockDim.x)
        deg[i] = 1.0f / sqrtf(deg[i]);
}

// ============================ launch ============================

extern "C" void kernel_launch(void* const* d_in, const int* in_sizes, int n_in,
                              void* d_out, int out_size, void* d_ws, size_t ws_size,
                              hipStream_t stream) {
    const float* edge_weight = (const float*)d_in[0];
    const int*   src         = (const int*)d_in[1];
    const int*   dst         = (const int*)d_in[2];
    const int*   pN          = (const int*)d_in[3];
    float* out = (float*)d_out;
    const int E = in_sizes[0];

    const int nBlocksEdges = (E / 4 + TPB - 1) / TPB;
    const unsigned long long need = OFF_PAIRS + 16ull * (unsigned long long)E;

    if ((unsigned long long)ws_size >= need) {
        unsigned* meta = (unsigned*)d_ws;
        float* part = (float*)((char*)d_ws + OFF_PART);
        float* norm = (float*)((char*)d_ws + OFF_NORM);
        uint2* pairs = (uint2*)((char*)d_ws + OFF_PAIRS);

        ewn_meta_zero<<<2, TPB, 0, stream>>>(meta);
        ewn_count_kernel<<<2048, TPB, 0, stream>>>(src, dst, meta, E);
        ewn_scan_kernel<<<1, 64, 0, stream>>>(meta, pN);
        ewn_partition_kernel<<<512, TPB, 0, stream>>>(edge_weight, src, dst, meta, pairs, E);
        ewn_accum_kernel<<<512, TPB, 0, stream>>>(pairs, meta, part, pN, E);
        ewn_reduce_kernel<<<512, TPB, 0, stream>>>(part, norm, pN);
        ewn_gather_kernel<<<nBlocksEdges, TPB, 0, stream>>>(edge_weight, src, dst, norm, pN, out, E);
    } else {
        float* deg = (float*)d_ws;
        ewn_fb_zero<<<1024, TPB, 0, stream>>>(deg, pN);
        ewn_fb_scatter<<<nBlocksEdges, TPB, 0, stream>>>(edge_weight, src, dst, deg, pN, E);
        ewn_fb_norm<<<1024, TPB, 0, stream>>>(deg, pN);
        ewn_gather_kernel<<<nBlocksEdges, TPB, 0, stream>>>(edge_weight, src, dst, deg, pN, out, E);
    }
}